// Round 1
// baseline (733.477 us; speedup 1.0000x reference)
//
#include <hip/hip_runtime.h>
#include <cstdint>
#include <cstddef>

typedef __bf16 bf16;
typedef __bf16 bf16x8 __attribute__((ext_vector_type(8)));
typedef __bf16 bf16x4 __attribute__((ext_vector_type(4)));
typedef float  f32x4  __attribute__((ext_vector_type(4)));

#define D_MODEL 1024
#define D_FF    4096
#define SEQ     2048
#define NB      4
#define NH      16
#define DKH     64
#define MTOT    (NB * SEQ) /* 8192 */

// async global->LDS, 16B per lane; LDS dest is wave-uniform base + lane*16
__device__ __forceinline__ void gl_lds16(const void* g, void* l) {
  __builtin_amdgcn_global_load_lds(
      (__attribute__((address_space(1))) unsigned int*)(void*)g,
      (__attribute__((address_space(3))) unsigned int*)l, 16, 0, 0);
}

// XOR swizzle for 128-byte-row LDS tiles (G4 recipe): spreads rows across banks
#define SWZ(row, kb) (((row) << 7) + ((kb) ^ (((row) & 7) << 4)))

// ---------------- transpose + fp32->bf16: Wt[c][r] = W[r][c] ----------------
__global__ __launch_bounds__(256) void k_transp(const float* __restrict__ W,
                                                bf16* __restrict__ Wt, int R, int C) {
  __shared__ float tile[32][33];
  const int c0 = blockIdx.x * 32, r0 = blockIdx.y * 32;
  const int t = threadIdx.x;
  const int rl = t >> 5, cl = t & 31;
#pragma unroll
  for (int i = 0; i < 4; ++i)
    tile[rl + i * 8][cl] = W[(size_t)(r0 + rl + i * 8) * C + c0 + cl];
  __syncthreads();
#pragma unroll
  for (int i = 0; i < 4; ++i)
    Wt[(size_t)(c0 + rl + i * 8) * R + r0 + cl] = (bf16)tile[cl][rl + i * 8];
}

// ---------------- LayerNorm fp32 -> bf16 (one block per row) ----------------
__global__ __launch_bounds__(256) void k_ln(const float* __restrict__ x,
                                            const float* __restrict__ g,
                                            const float* __restrict__ b,
                                            bf16* __restrict__ out) {
  const int row = blockIdx.x;
  const int t = threadIdx.x;
  const float4 v = ((const float4*)(x + (size_t)row * D_MODEL))[t];
  float s  = v.x + v.y + v.z + v.w;
  float s2 = v.x * v.x + v.y * v.y + v.z * v.z + v.w * v.w;
#pragma unroll
  for (int off = 1; off < 64; off <<= 1) {
    s  += __shfl_xor(s, off);
    s2 += __shfl_xor(s2, off);
  }
  __shared__ float red[8];
  const int wv = t >> 6;
  if ((t & 63) == 0) { red[wv] = s; red[4 + wv] = s2; }
  __syncthreads();
  s  = red[0] + red[1] + red[2] + red[3];
  s2 = red[4] + red[5] + red[6] + red[7];
  const float mu   = s * (1.f / D_MODEL);
  const float var  = s2 * (1.f / D_MODEL) - mu * mu;
  const float rstd = rsqrtf(var + 1e-6f);
  const float4 gv = ((const float4*)g)[t];
  const float4 bv = ((const float4*)b)[t];
  bf16x4 o;
  o[0] = (bf16)((v.x - mu) * rstd * gv.x + bv.x);
  o[1] = (bf16)((v.y - mu) * rstd * gv.y + bv.y);
  o[2] = (bf16)((v.z - mu) * rstd * gv.z + bv.z);
  o[3] = (bf16)((v.w - mu) * rstd * gv.w + bv.w);
  *(bf16x4*)(out + (size_t)row * D_MODEL + t * 4) = o;
}

// ---------------- m97-style GEMM: C = A(MxK) * Bt(NxK)^T + bias -------------
// EPI: 1 = qkv scatter (alpha applied), 2 = +resid -> fp32, 3 = relu -> bf16
template <int EPI>
__global__ __launch_bounds__(256) void k_gemm(
    const bf16* __restrict__ A, const bf16* __restrict__ Bt,
    const float* __restrict__ bias, float alpha,
    bf16* __restrict__ obf, float* __restrict__ of32,
    const float* __restrict__ resid,
    int M, int N, int K) {
  __shared__ bf16 As[128 * 32];
  __shared__ bf16 Bs[128 * 32];
  const int t = threadIdx.x, lane = t & 63, w = t >> 6;
  const int wr = w >> 1, wc = w & 1;
  const int tm = blockIdx.y * 128, tn = blockIdx.x * 128;

  f32x4 acc[4][4] = {};

  // staging: issue p = w*2+i covers rows p*16 + lane/4, cols (lane&3)*8
  const int arow = w * 32 + (lane >> 2);
  const int acol = (lane & 3) * 8;
  const bf16* aS0 = A  + (size_t)(tm + arow) * K + acol;
  const bf16* aS1 = aS0 + (size_t)16 * K;
  const bf16* bS0 = Bt + (size_t)(tn + arow) * K + acol;
  const bf16* bS1 = bS0 + (size_t)16 * K;
  bf16* aD0 = (bf16*)As + w * 1024;
  bf16* aD1 = aD0 + 512;
  bf16* bD0 = (bf16*)Bs + w * 1024;
  bf16* bD1 = bD0 + 512;

  const bf16* aRd[4];
  const bf16* bRd[4];
#pragma unroll
  for (int m = 0; m < 4; ++m)
    aRd[m] = As + (wr * 64 + m * 16 + (lane & 15)) * 32 + (lane >> 4) * 8;
#pragma unroll
  for (int n = 0; n < 4; ++n)
    bRd[n] = Bs + (wc * 64 + n * 16 + (lane & 15)) * 32 + (lane >> 4) * 8;

  for (int k0 = 0; k0 < K; k0 += 32) {
    __syncthreads();
    gl_lds16(aS0 + k0, aD0);
    gl_lds16(aS1 + k0, aD1);
    gl_lds16(bS0 + k0, bD0);
    gl_lds16(bS1 + k0, bD1);
    __syncthreads();
    bf16x8 af[4], bfr[4];
#pragma unroll
    for (int m = 0; m < 4; ++m) af[m] = *(const bf16x8*)aRd[m];
#pragma unroll
    for (int n = 0; n < 4; ++n) bfr[n] = *(const bf16x8*)bRd[n];
#pragma unroll
    for (int m = 0; m < 4; ++m)
#pragma unroll
      for (int n = 0; n < 4; ++n)
        acc[m][n] = __builtin_amdgcn_mfma_f32_16x16x32_bf16(af[m], bfr[n], acc[m][n], 0, 0, 0);
  }

  const int row0 = tm + wr * 64 + (lane >> 4) * 4;
  const int col0 = tn + wc * 64 + (lane & 15);
#pragma unroll
  for (int n = 0; n < 4; ++n) {
    const int col = col0 + n * 16;
    const float bv = bias[col];
#pragma unroll
    for (int m = 0; m < 4; ++m) {
#pragma unroll
      for (int r = 0; r < 4; ++r) {
        const int row = row0 + m * 16 + r;
        float val = acc[m][n][r] + bv;
        if constexpr (EPI == 1) {
          const int bb = row >> 11, ss = row & 2047, hh = col >> 6, dd = col & 63;
          obf[(((size_t)bb * NH + hh) * SEQ + ss) * DKH + dd] = (bf16)(val * alpha);
        } else if constexpr (EPI == 2) {
          const size_t idx = (size_t)row * N + col;
          of32[idx] = resid[idx] + val;
        } else {
          obf[(size_t)row * N + col] = (bf16)fmaxf(val, 0.f);
        }
      }
    }
  }
}

// ---------------- flash attention (bf16 MFMA, fp32 online softmax) ----------
// q,k,v: (B,H,S,64) bf16. ctx out: (B*S, 1024) bf16. grid = (16 q-tiles, 64 bh)
__global__ __launch_bounds__(256) void k_attn(
    const bf16* __restrict__ q, const bf16* __restrict__ k, const bf16* __restrict__ v,
    const int* __restrict__ emask, bf16* __restrict__ ctx) {
  __shared__ bf16 Kl[64 * 64];       // swizzled [key][dk]
  __shared__ bf16 Vt[64 * 64];       // swizzled [dk][key]
  __shared__ bf16 Pl[4][32 * 64];    // per-wave swizzled [qrow][key]
  const int t = threadIdx.x, lane = t & 63, w = t >> 6;
  const int bh = blockIdx.y, b = bh >> 4, h = bh & 15;
  const int q0 = blockIdx.x * 128;
  const bf16* qp = q + (size_t)bh * SEQ * DKH;
  const bf16* kp = k + (size_t)bh * SEQ * DKH;
  const bf16* vp = v + (size_t)bh * SEQ * DKH;
  const int* mp = emask + b * SEQ;

  bf16x8 qf[2][2];
#pragma unroll
  for (int fm = 0; fm < 2; ++fm) {
    const bf16* qbase = qp + (size_t)(q0 + w * 32 + fm * 16 + (lane & 15)) * DKH + (lane >> 4) * 8;
    qf[fm][0] = *(const bf16x8*)qbase;
    qf[fm][1] = *(const bf16x8*)(qbase + 32);
  }

  float mrun[2][4], lrun[2][4];
  f32x4 o[2][4] = {};
#pragma unroll
  for (int fm = 0; fm < 2; ++fm)
#pragma unroll
    for (int r = 0; r < 4; ++r) { mrun[fm][r] = -1e30f; lrun[fm][r] = 0.f; }

  // K staging: issue p=w*2+i -> phys row p*8 + lane/8, phys col-byte (lane&7)*16
  const int krow  = w * 16 + (lane >> 3);
  const int kcolb = ((lane & 7) * 16) ^ ((krow & 7) << 4);  // logical dk-byte (pre-swizzled src)
  const bf16* kS0 = kp + (size_t)krow * DKH + (kcolb >> 1);
  const bf16* kS1 = kS0 + 8 * DKH;
  bf16* kD0 = (bf16*)Kl + w * 1024;
  bf16* kD1 = kD0 + 512;

  const int vrow = t >> 2, vd0 = (t & 3) * 16;
  const bf16* vS = vp + (size_t)vrow * DKH + vd0;

  for (int kb = 0; kb < SEQ; kb += 64) {
    __syncthreads();
    gl_lds16(kS0 + (size_t)kb * DKH, kD0);
    gl_lds16(kS1 + (size_t)kb * DKH, kD1);
    const bf16x8 v0 = *(const bf16x8*)(vS + (size_t)kb * DKH);
    const bf16x8 v1 = *(const bf16x8*)(vS + (size_t)kb * DKH + 8);
#pragma unroll
    for (int j = 0; j < 8; ++j) {
      *(bf16*)((char*)Vt + SWZ(vd0 + j,     vrow * 2)) = v0[j];
      *(bf16*)((char*)Vt + SWZ(vd0 + 8 + j, vrow * 2)) = v1[j];
    }
    __syncthreads();

    // QK^T (q pre-scaled by 1/8 in the Q GEMM epilogue)
    f32x4 sc[2][4];
#pragma unroll
    for (int fn = 0; fn < 4; ++fn) {
      const bf16x8 kf0 = *(const bf16x8*)((const char*)Kl + SWZ(fn * 16 + (lane & 15), (lane >> 4) * 16));
      const bf16x8 kf1 = *(const bf16x8*)((const char*)Kl + SWZ(fn * 16 + (lane & 15), 64 + (lane >> 4) * 16));
#pragma unroll
      for (int fm = 0; fm < 2; ++fm) {
        f32x4 z = {};
        z = __builtin_amdgcn_mfma_f32_16x16x32_bf16(qf[fm][0], kf0, z, 0, 0, 0);
        z = __builtin_amdgcn_mfma_f32_16x16x32_bf16(qf[fm][1], kf1, z, 0, 0, 0);
        sc[fm][fn] = z;
      }
    }
    // mask
#pragma unroll
    for (int fn = 0; fn < 4; ++fn) {
      if (mp[kb + fn * 16 + (lane & 15)] == 0) {
#pragma unroll
        for (int r = 0; r < 4; ++r) { sc[0][fn][r] = -1e9f; sc[1][fn][r] = -1e9f; }
      }
    }
    // online softmax; P -> LDS (bf16, swizzled)
#pragma unroll
    for (int fm = 0; fm < 2; ++fm) {
#pragma unroll
      for (int r = 0; r < 4; ++r) {
        float mx = fmaxf(fmaxf(sc[fm][0][r], sc[fm][1][r]), fmaxf(sc[fm][2][r], sc[fm][3][r]));
        for (int off = 1; off < 16; off <<= 1) mx = fmaxf(mx, __shfl_xor(mx, off));
        const float mnew = fmaxf(mrun[fm][r], mx);
        const float scal = __expf(mrun[fm][r] - mnew);
        mrun[fm][r] = mnew;
        float ls = 0.f;
#pragma unroll
        for (int fn = 0; fn < 4; ++fn) {
          const float p = __expf(sc[fm][fn][r] - mnew);
          sc[fm][fn][r] = p;
          ls += p;
        }
        for (int off = 1; off < 16; off <<= 1) ls += __shfl_xor(ls, off);
        lrun[fm][r] = lrun[fm][r] * scal + ls;
#pragma unroll
        for (int fd = 0; fd < 4; ++fd) o[fm][fd][r] = o[fm][fd][r] * scal;
      }
      char* pb = (char*)Pl[w];
#pragma unroll
      for (int fn = 0; fn < 4; ++fn)
#pragma unroll
        for (int r = 0; r < 4; ++r)
          *(bf16*)(pb + SWZ(fm * 16 + (lane >> 4) * 4 + r, (fn * 16 + (lane & 15)) * 2)) =
              (bf16)sc[fm][fn][r];
    }
    // P @ V
#pragma unroll
    for (int kk = 0; kk < 2; ++kk) {
      bf16x8 pa[2];
#pragma unroll
      for (int fm = 0; fm < 2; ++fm)
        pa[fm] = *(const bf16x8*)((const char*)Pl[w] + SWZ(fm * 16 + (lane & 15), kk * 64 + (lane >> 4) * 16));
#pragma unroll
      for (int fd = 0; fd < 4; ++fd) {
        const bf16x8 vf = *(const bf16x8*)((const char*)Vt + SWZ(fd * 16 + (lane & 15), kk * 64 + (lane >> 4) * 16));
#pragma unroll
        for (int fm = 0; fm < 2; ++fm)
          o[fm][fd] = __builtin_amdgcn_mfma_f32_16x16x32_bf16(pa[fm], vf, o[fm][fd], 0, 0, 0);
      }
    }
  }

#pragma unroll
  for (int fm = 0; fm < 2; ++fm)
#pragma unroll
    for (int fd = 0; fd < 4; ++fd)
#pragma unroll
      for (int r = 0; r < 4; ++r) {
        const int srow = q0 + w * 32 + fm * 16 + (lane >> 4) * 4 + r;
        const int col  = h * 64 + fd * 16 + (lane & 15);
        ctx[((size_t)b * SEQ + srow) * D_MODEL + col] = (bf16)(o[fm][fd][r] / lrun[fm][r]);
      }
}

// ---------------------------------------------------------------------------
extern "C" void kernel_launch(void* const* d_in, const int* in_sizes, int n_in,
                              void* d_out, int out_size, void* d_ws, size_t ws_size,
                              hipStream_t stream) {
  (void)in_sizes; (void)n_in; (void)out_size; (void)ws_size;
  const float* x    = (const float*)d_in[0];
  const int*   em   = (const int*)d_in[1];
  const float* ln1g = (const float*)d_in[2];
  const float* ln1b = (const float*)d_in[3];
  const float* wq   = (const float*)d_in[4];
  const float* bq   = (const float*)d_in[5];
  const float* wk   = (const float*)d_in[6];
  const float* bk   = (const float*)d_in[7];
  const float* wv   = (const float*)d_in[8];
  const float* bv   = (const float*)d_in[9];
  const float* w0   = (const float*)d_in[10];
  const float* b0   = (const float*)d_in[11];
  const float* ln2g = (const float*)d_in[12];
  const float* ln2b = (const float*)d_in[13];
  const float* w1   = (const float*)d_in[14];
  const float* b1   = (const float*)d_in[15];
  const float* w2   = (const float*)d_in[16];
  const float* b2   = (const float*)d_in[17];
  float* out = (float*)d_out;

  char* ws = (char*)d_ws;
  const size_t MB = 1u << 20;
  bf16* wqT = (bf16*)(ws + 0 * MB);    // [1024][1024]
  bf16* wkT = (bf16*)(ws + 2 * MB);
  bf16* wvT = (bf16*)(ws + 4 * MB);
  bf16* w0T = (bf16*)(ws + 6 * MB);
  bf16* w1T = (bf16*)(ws + 8 * MB);    // [4096][1024]
  bf16* w2T = (bf16*)(ws + 16 * MB);   // [1024][4096]
  bf16* x1  = (bf16*)(ws + 24 * MB);   // LN out (reused for LN2 out)
  bf16* qB  = (bf16*)(ws + 40 * MB);   // (B,H,S,64)
  bf16* kB  = (bf16*)(ws + 56 * MB);
  bf16* vB  = (bf16*)(ws + 72 * MB);
  bf16* cB  = (bf16*)(ws + 88 * MB);   // ctx (M,1024)
  bf16* hB  = (bf16*)(ws + 40 * MB);   // FFN hidden (M,4096) overlays dead q/k/v/ctx

  // weight transpose+convert (per-call; stateless)
  k_transp<<<dim3(32, 32),  256, 0, stream>>>(wq, wqT, 1024, 1024);
  k_transp<<<dim3(32, 32),  256, 0, stream>>>(wk, wkT, 1024, 1024);
  k_transp<<<dim3(32, 32),  256, 0, stream>>>(wv, wvT, 1024, 1024);
  k_transp<<<dim3(32, 32),  256, 0, stream>>>(w0, w0T, 1024, 1024);
  k_transp<<<dim3(128, 32), 256, 0, stream>>>(w1, w1T, 1024, 4096);
  k_transp<<<dim3(32, 128), 256, 0, stream>>>(w2, w2T, 4096, 1024);

  k_ln<<<MTOT, 256, 0, stream>>>(x, ln1g, ln1b, x1);

  const dim3 g1024(1024 / 128, MTOT / 128);  // (8, 64)
  // q gets 1/sqrt(d_k)=0.125 folded in after bias
  k_gemm<1><<<g1024, 256, 0, stream>>>(x1, wqT, bq, 0.125f, qB, nullptr, nullptr, MTOT, 1024, 1024);
  k_gemm<1><<<g1024, 256, 0, stream>>>(x1, wkT, bk, 1.0f,   kB, nullptr, nullptr, MTOT, 1024, 1024);
  k_gemm<1><<<g1024, 256, 0, stream>>>(x1, wvT, bv, 1.0f,   vB, nullptr, nullptr, MTOT, 1024, 1024);

  k_attn<<<dim3(16, 64), 256, 0, stream>>>(qB, kB, vB, em, cB);

  // x := x + ctx @ w0 + b0  (fp32 residual stream lives in d_out)
  k_gemm<2><<<g1024, 256, 0, stream>>>(cB, w0T, b0, 1.0f, nullptr, out, x, MTOT, 1024, 1024);

  k_ln<<<MTOT, 256, 0, stream>>>(out, ln2g, ln2b, x1);

  // h = relu(x2 @ w1 + b1)
  k_gemm<3><<<dim3(4096 / 128, MTOT / 128), 256, 0, stream>>>(x1, w1T, b1, 1.0f, hB, nullptr, nullptr, MTOT, 4096, 1024);

  // out := out + h @ w2 + b2
  k_gemm<2><<<g1024, 256, 0, stream>>>(hB, w2T, b2, 1.0f, nullptr, out, out, MTOT, 1024, 4096);
}

// Round 2
// 639.425 us; speedup vs baseline: 1.1471x; 1.1471x over previous
//
#include <hip/hip_runtime.h>
#include <cstdint>
#include <cstddef>

typedef __bf16 bf16;
typedef __bf16 bf16x8 __attribute__((ext_vector_type(8)));
typedef __bf16 bf16x4 __attribute__((ext_vector_type(4)));
typedef float  f32x4  __attribute__((ext_vector_type(4)));
typedef float  f32x16 __attribute__((ext_vector_type(16)));

#define D_MODEL 1024
#define D_FF    4096
#define SEQ     2048
#define NB      4
#define NH      16
#define DKH     64
#define MTOT    (NB * SEQ) /* 8192 */

// async global->LDS, 16B per lane; LDS dest is wave-uniform base + lane*16
__device__ __forceinline__ void gl_lds16(const void* g, void* l) {
  __builtin_amdgcn_global_load_lds(
      (__attribute__((address_space(1))) unsigned int*)(void*)g,
      (__attribute__((address_space(3))) unsigned int*)l, 16, 0, 0);
}

// XOR swizzle for 128-byte-row LDS tiles (G4 recipe)
#define SWZ(row, kb) (((row) << 7) + ((kb) ^ (((row) & 7) << 4)))

__device__ __forceinline__ unsigned cvtpk(float lo, float hi_) {
  unsigned r;
  asm("v_cvt_pk_bf16_f32 %0, %1, %2" : "=v"(r) : "v"(lo), "v"(hi_));
  return r;
}
// a' = [a_lo | b_lo], b' = [a_hi | b_hi]
__device__ __forceinline__ void pl32swap(unsigned& a, unsigned& b) {
  asm volatile("v_permlane32_swap_b32 %0, %1" : "+v"(a), "+v"(b));
}

// ---------------- transpose + fp32->bf16: Wt[c][r] = W[r][c] ----------------
__global__ __launch_bounds__(256) void k_transp(const float* __restrict__ W,
                                                bf16* __restrict__ Wt, int R, int C) {
  __shared__ float tile[32][33];
  const int c0 = blockIdx.x * 32, r0 = blockIdx.y * 32;
  const int t = threadIdx.x;
  const int rl = t >> 5, cl = t & 31;
#pragma unroll
  for (int i = 0; i < 4; ++i)
    tile[rl + i * 8][cl] = W[(size_t)(r0 + rl + i * 8) * C + c0 + cl];
  __syncthreads();
#pragma unroll
  for (int i = 0; i < 4; ++i)
    Wt[(size_t)(c0 + rl + i * 8) * R + r0 + cl] = (bf16)tile[cl][rl + i * 8];
}

// ---------------- LayerNorm fp32 -> bf16 (one block per row) ----------------
__global__ __launch_bounds__(256) void k_ln(const float* __restrict__ x,
                                            const float* __restrict__ g,
                                            const float* __restrict__ b,
                                            bf16* __restrict__ out) {
  const int row = blockIdx.x;
  const int t = threadIdx.x;
  const float4 v = ((const float4*)(x + (size_t)row * D_MODEL))[t];
  float s  = v.x + v.y + v.z + v.w;
  float s2 = v.x * v.x + v.y * v.y + v.z * v.z + v.w * v.w;
#pragma unroll
  for (int off = 1; off < 64; off <<= 1) {
    s  += __shfl_xor(s, off);
    s2 += __shfl_xor(s2, off);
  }
  __shared__ float red[8];
  const int wv = t >> 6;
  if ((t & 63) == 0) { red[wv] = s; red[4 + wv] = s2; }
  __syncthreads();
  s  = red[0] + red[1] + red[2] + red[3];
  s2 = red[4] + red[5] + red[6] + red[7];
  const float mu   = s * (1.f / D_MODEL);
  const float var  = s2 * (1.f / D_MODEL) - mu * mu;
  const float rstd = rsqrtf(var + 1e-6f);
  const float4 gv = ((const float4*)g)[t];
  const float4 bv = ((const float4*)b)[t];
  bf16x4 o;
  o[0] = (bf16)((v.x - mu) * rstd * gv.x + bv.x);
  o[1] = (bf16)((v.y - mu) * rstd * gv.y + bv.y);
  o[2] = (bf16)((v.z - mu) * rstd * gv.z + bv.z);
  o[3] = (bf16)((v.w - mu) * rstd * gv.w + bv.w);
  *(bf16x4*)(out + (size_t)row * D_MODEL + t * 4) = o;
}

// ---------------- m97-style GEMM: C = A(MxK) * Bt(NxK)^T + bias -------------
// EPI: 1 = fused qkv scatter (which = tn>>10), 2 = +resid -> fp32, 3 = relu -> bf16
template <int EPI>
__global__ __launch_bounds__(256) void k_gemm(
    const bf16* __restrict__ A, const bf16* __restrict__ Bt,
    const float* __restrict__ bias, const float* __restrict__ biasK,
    const float* __restrict__ biasV, float alpha,
    bf16* __restrict__ obf, float* __restrict__ of32,
    const float* __restrict__ resid,
    int M, int N, int K) {
  __shared__ bf16 As[128 * 32];
  __shared__ bf16 Bs[128 * 32];
  const int t = threadIdx.x, lane = t & 63, w = t >> 6;
  const int wr = w >> 1, wc = w & 1;
  const int tm = blockIdx.y * 128, tn = blockIdx.x * 128;

  f32x4 acc[4][4] = {};

  const int arow = w * 32 + (lane >> 2);
  const int acol = (lane & 3) * 8;
  const bf16* aS0 = A  + (size_t)(tm + arow) * K + acol;
  const bf16* aS1 = aS0 + (size_t)16 * K;
  const bf16* bS0 = Bt + (size_t)(tn + arow) * K + acol;
  const bf16* bS1 = bS0 + (size_t)16 * K;
  bf16* aD0 = (bf16*)As + w * 1024;
  bf16* aD1 = aD0 + 512;
  bf16* bD0 = (bf16*)Bs + w * 1024;
  bf16* bD1 = bD0 + 512;

  const bf16* aRd[4];
  const bf16* bRd[4];
#pragma unroll
  for (int m = 0; m < 4; ++m)
    aRd[m] = As + (wr * 64 + m * 16 + (lane & 15)) * 32 + (lane >> 4) * 8;
#pragma unroll
  for (int n = 0; n < 4; ++n)
    bRd[n] = Bs + (wc * 64 + n * 16 + (lane & 15)) * 32 + (lane >> 4) * 8;

  for (int k0 = 0; k0 < K; k0 += 32) {
    __syncthreads();
    gl_lds16(aS0 + k0, aD0);
    gl_lds16(aS1 + k0, aD1);
    gl_lds16(bS0 + k0, bD0);
    gl_lds16(bS1 + k0, bD1);
    __syncthreads();
    bf16x8 af[4], bfr[4];
#pragma unroll
    for (int m = 0; m < 4; ++m) af[m] = *(const bf16x8*)aRd[m];
#pragma unroll
    for (int n = 0; n < 4; ++n) bfr[n] = *(const bf16x8*)bRd[n];
#pragma unroll
    for (int m = 0; m < 4; ++m)
#pragma unroll
      for (int n = 0; n < 4; ++n)
        acc[m][n] = __builtin_amdgcn_mfma_f32_16x16x32_bf16(af[m], bfr[n], acc[m][n], 0, 0, 0);
  }

  const int row0 = tm + wr * 64 + (lane >> 4) * 4;
  const int col0 = tn + wc * 64 + (lane & 15);
  // EPI==1 per-block uniform selection
  const int which = tn >> 10;
  const float* bp = (EPI == 1) ? (which == 0 ? bias : (which == 1 ? biasK : biasV)) : bias;
  const float af_ = (EPI == 1) ? (which == 0 ? alpha : 1.f) : alpha;
  bf16* qkvB = (EPI == 1) ? obf + (size_t)which * MTOT * D_MODEL : obf;
#pragma unroll
  for (int n = 0; n < 4; ++n) {
    const int col = col0 + n * 16;
    const float bv = (EPI == 1) ? bp[col & 1023] : bp[col];
#pragma unroll
    for (int m = 0; m < 4; ++m) {
#pragma unroll
      for (int r = 0; r < 4; ++r) {
        const int row = row0 + m * 16 + r;
        float val = acc[m][n][r] + bv;
        if constexpr (EPI == 1) {
          const int bb = row >> 11, ss = row & 2047, hh = (col >> 6) & 15, dd = col & 63;
          qkvB[(((size_t)bb * NH + hh) * SEQ + ss) * DKH + dd] = (bf16)(val * af_);
        } else if constexpr (EPI == 2) {
          const size_t idx = (size_t)row * N + col;
          of32[idx] = resid[idx] + val;
        } else {
          obf[(size_t)row * N + col] = (bf16)fmaxf(val, 0.f);
        }
      }
    }
  }
}

// ---------------- flash attention: swapped-operand 32x32 MFMA ---------------
// q,k,v: (B,H,S,64) bf16 (q pre-scaled by 0.125*log2e). ctx: (B*S,1024) bf16.
// grid = (64 bh, 8 q-tiles); block = 512 (8 warps x 32 q-rows = 256 rows)
__global__ __launch_bounds__(512, 4) void k_attn(
    const bf16* __restrict__ q, const bf16* __restrict__ k, const bf16* __restrict__ v,
    const int* __restrict__ emask, bf16* __restrict__ ctx) {
  __shared__ bf16 Kl[64 * 64];   // swizzled [key][dk]
  __shared__ bf16 Vt[64 * 64];   // swizzled [dk][key]
  __shared__ float Msk[64];
  __shared__ int MskFlag;
  const int t = threadIdx.x, lane = t & 63, w = t >> 6;
  const int hi = lane >> 5;
  const int l31 = lane & 31;
  const unsigned swz = (lane & 7) << 4;
  const int bh = blockIdx.x, b = bh >> 4, h = bh & 15;
  const int q0 = blockIdx.y * 256;
  const bf16* qp = q + (size_t)bh * SEQ * DKH;
  const bf16* kp = k + (size_t)bh * SEQ * DKH;
  const bf16* vp = v + (size_t)bh * SEQ * DKH;
  const int* mp = emask + b * SEQ;

  // Q fragments: lane owns q-row (q0 + w*32 + l31); B-operand k-range hi*8
  const int qrow = q0 + w * 32 + l31;
  const bf16* qpr = qp + (size_t)qrow * DKH + hi * 8;
  bf16x8 qf[4];
#pragma unroll
  for (int ks = 0; ks < 4; ++ks) qf[ks] = *(const bf16x8*)(qpr + ks * 16);

  // K stage: linear LDS dest, pre-swizzled global source (rule #21)
  const int krow = w * 8 + (lane >> 3);
  const int kcolE = (((lane & 7) * 16) ^ ((lane >> 3) << 4)) >> 1;
  const bf16* kSrc = kp + (size_t)krow * DKH + kcolE;
  char* kDst = (char*)Kl + w * 1024;

  // V stage: reg -> swizzled transposed LDS
  const int vKey = t >> 3, vD0 = (t & 7) * 8;
  const bf16* vSrc = vp + (size_t)vKey * DKH + vD0;

  f32x16 O0 = {}, O1 = {};
  float mrun = -3e38f, lrun = 0.f;

  for (int kt = 0; kt < SEQ; kt += 64) {
    __syncthreads();
    gl_lds16(kSrc + (size_t)kt * DKH, kDst);
    const bf16x8 vv = *(const bf16x8*)(vSrc + (size_t)kt * DKH);
#pragma unroll
    for (int j = 0; j < 8; ++j)
      *(bf16*)((char*)Vt + ((vD0 + j) << 7) + ((vKey * 2) ^ (j << 4))) = vv[j];
    if (t < 64) {
      const float mv = (mp[kt + t] == 0) ? -1e9f : 0.f;
      Msk[t] = mv;
      const unsigned long long bal = __ballot(mv != 0.f);
      if (t == 0) MskFlag = (bal != 0ull);
    }
    __syncthreads();

    // QK^T (swapped): S^T[key][q], col=lane&31=q
    f32x16 s0 = {}, s1 = {};
#pragma unroll
    for (int ks = 0; ks < 4; ++ks) {
      const bf16x8 kf = *(const bf16x8*)((const char*)Kl + (l31 << 7) + ((ks * 32 + hi * 16) ^ swz));
      s0 = __builtin_amdgcn_mfma_f32_32x32x16_bf16(kf, qf[ks], s0, 0, 0, 0);
    }
#pragma unroll
    for (int ks = 0; ks < 4; ++ks) {
      const bf16x8 kf = *(const bf16x8*)((const char*)Kl + ((32 + l31) << 7) + ((ks * 32 + hi * 16) ^ swz));
      s1 = __builtin_amdgcn_mfma_f32_32x32x16_bf16(kf, qf[ks], s1, 0, 0, 0);
    }
    if (MskFlag) {
#pragma unroll
      for (int g = 0; g < 4; ++g)
#pragma unroll
        for (int j = 0; j < 4; ++j) {
          s0[g * 4 + j] += Msk[g * 8 + hi * 4 + j];
          s1[g * 4 + j] += Msk[32 + g * 8 + hi * 4 + j];
        }
    }

    // online softmax (base-2 domain; log2e folded into Q scale)
    float mx = s0[0];
#pragma unroll
    for (int r = 1; r < 16; ++r) mx = fmaxf(mx, s0[r]);
#pragma unroll
    for (int r = 0; r < 16; ++r) mx = fmaxf(mx, s1[r]);
    mx = fmaxf(mx, __shfl_xor(mx, 32));
    const float mnew = fmaxf(mrun, mx);
    const float scal = exp2f(mrun - mnew);
    mrun = mnew;
    float ts = 0.f;
#pragma unroll
    for (int r = 0; r < 16; ++r) { const float p = exp2f(s0[r] - mnew); s0[r] = p; ts += p; }
#pragma unroll
    for (int r = 0; r < 16; ++r) { const float p = exp2f(s1[r] - mnew); s1[r] = p; ts += p; }
    ts += __shfl_xor(ts, 32);
    lrun = lrun * scal + ts;
#pragma unroll
    for (int r = 0; r < 16; ++r) { O0[r] *= scal; O1[r] *= scal; }

    // pack P^T fragment (cvt_pk + permlane32_swap) and PV (swapped): O^T[d][q]
#define PVSTEP(S, bsel, ks)                                                          \
    {                                                                                \
      unsigned c0 = cvtpk(S[8 * bsel + 0], S[8 * bsel + 1]);                         \
      unsigned c1 = cvtpk(S[8 * bsel + 2], S[8 * bsel + 3]);                         \
      unsigned c2 = cvtpk(S[8 * bsel + 4], S[8 * bsel + 5]);                         \
      unsigned c3 = cvtpk(S[8 * bsel + 6], S[8 * bsel + 7]);                         \
      pl32swap(c0, c2);                                                              \
      pl32swap(c1, c3);                                                              \
      union { unsigned u[4]; bf16x8 vv_; } pu = {{c0, c1, c2, c3}};                  \
      const bf16x8 vf0 = *(const bf16x8*)((const char*)Vt + (l31 << 7) + (((ks) * 32 + hi * 16) ^ swz)); \
      O0 = __builtin_amdgcn_mfma_f32_32x32x16_bf16(vf0, pu.vv_, O0, 0, 0, 0);        \
      const bf16x8 vf1 = *(const bf16x8*)((const char*)Vt + ((32 + l31) << 7) + (((ks) * 32 + hi * 16) ^ swz)); \
      O1 = __builtin_amdgcn_mfma_f32_32x32x16_bf16(vf1, pu.vv_, O1, 0, 0, 0);        \
    }
    PVSTEP(s0, 0, 0)
    PVSTEP(s0, 1, 1)
    PVSTEP(s1, 0, 2)
    PVSTEP(s1, 1, 3)
#undef PVSTEP
  }

  const float rl = 1.f / lrun;
  bf16* cp = ctx + ((size_t)b * SEQ + qrow) * D_MODEL + h * 64;
#pragma unroll
  for (int r = 0; r < 16; ++r) {
    const int d0 = (r & 3) + 8 * (r >> 2) + hi * 4;
    cp[d0]      = (bf16)(O0[r] * rl);
    cp[32 + d0] = (bf16)(O1[r] * rl);
  }
}

// ---------------------------------------------------------------------------
extern "C" void kernel_launch(void* const* d_in, const int* in_sizes, int n_in,
                              void* d_out, int out_size, void* d_ws, size_t ws_size,
                              hipStream_t stream) {
  (void)in_sizes; (void)n_in; (void)out_size; (void)ws_size;
  const float* x    = (const float*)d_in[0];
  const int*   em   = (const int*)d_in[1];
  const float* ln1g = (const float*)d_in[2];
  const float* ln1b = (const float*)d_in[3];
  const float* wq   = (const float*)d_in[4];
  const float* bq   = (const float*)d_in[5];
  const float* wk   = (const float*)d_in[6];
  const float* bk   = (const float*)d_in[7];
  const float* wv   = (const float*)d_in[8];
  const float* bv   = (const float*)d_in[9];
  const float* w0   = (const float*)d_in[10];
  const float* b0   = (const float*)d_in[11];
  const float* ln2g = (const float*)d_in[12];
  const float* ln2b = (const float*)d_in[13];
  const float* w1   = (const float*)d_in[14];
  const float* b1   = (const float*)d_in[15];
  const float* w2   = (const float*)d_in[16];
  const float* b2   = (const float*)d_in[17];
  float* out = (float*)d_out;

  char* ws = (char*)d_ws;
  const size_t MB = 1u << 20;
  bf16* wqT = (bf16*)(ws + 0 * MB);    // [3072][1024] contiguous q,k,v
  bf16* wkT = (bf16*)(ws + 2 * MB);
  bf16* wvT = (bf16*)(ws + 4 * MB);
  bf16* w0T = (bf16*)(ws + 6 * MB);
  bf16* w1T = (bf16*)(ws + 8 * MB);    // [4096][1024]
  bf16* w2T = (bf16*)(ws + 16 * MB);   // [1024][4096]
  bf16* x1  = (bf16*)(ws + 24 * MB);   // LN out (reused for LN2 out)
  bf16* qB  = (bf16*)(ws + 40 * MB);   // (B,H,S,64) x3 contiguous
  bf16* kB  = (bf16*)(ws + 56 * MB);
  bf16* vB  = (bf16*)(ws + 72 * MB);
  bf16* cB  = (bf16*)(ws + 88 * MB);   // ctx (M,1024)
  bf16* hB  = (bf16*)(ws + 40 * MB);   // FFN hidden overlays dead q/k/v/ctx

  k_transp<<<dim3(32, 32),  256, 0, stream>>>(wq, wqT, 1024, 1024);
  k_transp<<<dim3(32, 32),  256, 0, stream>>>(wk, wkT, 1024, 1024);
  k_transp<<<dim3(32, 32),  256, 0, stream>>>(wv, wvT, 1024, 1024);
  k_transp<<<dim3(32, 32),  256, 0, stream>>>(w0, w0T, 1024, 1024);
  k_transp<<<dim3(128, 32), 256, 0, stream>>>(w1, w1T, 1024, 4096);
  k_transp<<<dim3(32, 128), 256, 0, stream>>>(w2, w2T, 4096, 1024);

  k_ln<<<MTOT, 256, 0, stream>>>(x, ln1g, ln1b, x1);

  // fused QKV: N=3072; q scaled by 0.125*log2(e) for base-2 softmax
  k_gemm<1><<<dim3(24, MTOT / 128), 256, 0, stream>>>(
      x1, wqT, bq, bk, bv, 0.125f * 1.44269504f, qB, nullptr, nullptr, MTOT, 3072, 1024);

  k_attn<<<dim3(64, 8), 512, 0, stream>>>(qB, kB, vB, em, cB);

  const dim3 g1024(8, MTOT / 128);
  k_gemm<2><<<g1024, 256, 0, stream>>>(cB, w0T, b0, nullptr, nullptr, 1.0f, nullptr, out, x, MTOT, 1024, 1024);

  k_ln<<<MTOT, 256, 0, stream>>>(out, ln2g, ln2b, x1);

  k_gemm<3><<<dim3(32, MTOT / 128), 256, 0, stream>>>(x1, w1T, b1, nullptr, nullptr, 1.0f, hB, nullptr, nullptr, MTOT, 4096, 1024);

  k_gemm<2><<<g1024, 256, 0, stream>>>(hB, w2T, b2, nullptr, nullptr, 1.0f, nullptr, out, out, MTOT, 1024, 4096);
}

// Round 4
// 545.703 us; speedup vs baseline: 1.3441x; 1.1717x over previous
//
#include <hip/hip_runtime.h>
#include <cstdint>
#include <cstddef>

typedef __bf16 bf16;
typedef __bf16 bf16x8 __attribute__((ext_vector_type(8)));
typedef __bf16 bf16x4 __attribute__((ext_vector_type(4)));
typedef float  f32x4  __attribute__((ext_vector_type(4)));
typedef float  f32x16 __attribute__((ext_vector_type(16)));

#define D_MODEL 1024
#define D_FF    4096
#define SEQ     2048
#define NB      4
#define NH      16
#define DKH     64
#define MTOT    (NB * SEQ) /* 8192 */

// async global->LDS, 16B per lane; LDS dest is wave-uniform base (+ lane*16 by HW)
__device__ __forceinline__ void gl_lds16(const void* g, void* l) {
  __builtin_amdgcn_global_load_lds(
      (__attribute__((address_space(1))) unsigned int*)(void*)g,
      (__attribute__((address_space(3))) unsigned int*)l, 16, 0, 0);
}

__device__ __forceinline__ unsigned cvtpk(float lo, float hi_) {
  unsigned r;
  asm("v_cvt_pk_bf16_f32 %0, %1, %2" : "=v"(r) : "v"(lo), "v"(hi_));
  return r;
}
__device__ __forceinline__ void pl32swap(unsigned& a, unsigned& b) {
  asm volatile("v_permlane32_swap_b32 %0, %1" : "+v"(a), "+v"(b));
}

// ---------------- transpose + fp32->bf16: Wt[c][r] = W[r][c] ----------------
__global__ __launch_bounds__(256) void k_transp(const float* __restrict__ W,
                                                bf16* __restrict__ Wt, int R, int C) {
  __shared__ float tile[32][33];
  const int c0 = blockIdx.x * 32, r0 = blockIdx.y * 32;
  const int t = threadIdx.x;
  const int rl = t >> 5, cl = t & 31;
#pragma unroll
  for (int i = 0; i < 4; ++i)
    tile[rl + i * 8][cl] = W[(size_t)(r0 + rl + i * 8) * C + c0 + cl];
  __syncthreads();
#pragma unroll
  for (int i = 0; i < 4; ++i)
    Wt[(size_t)(c0 + rl + i * 8) * R + r0 + cl] = (bf16)tile[cl][rl + i * 8];
}

// ---------------- LayerNorm fp32 -> bf16 (one block per row) ----------------
__global__ __launch_bounds__(256) void k_ln(const float* __restrict__ x,
                                            const float* __restrict__ g,
                                            const float* __restrict__ b,
                                            bf16* __restrict__ out) {
  const int row = blockIdx.x;
  const int t = threadIdx.x;
  const float4 v = ((const float4*)(x + (size_t)row * D_MODEL))[t];
  float s  = v.x + v.y + v.z + v.w;
  float s2 = v.x * v.x + v.y * v.y + v.z * v.z + v.w * v.w;
#pragma unroll
  for (int off = 1; off < 64; off <<= 1) {
    s  += __shfl_xor(s, off);
    s2 += __shfl_xor(s2, off);
  }
  __shared__ float red[8];
  const int wv = t >> 6;
  if ((t & 63) == 0) { red[wv] = s; red[4 + wv] = s2; }
  __syncthreads();
  s  = red[0] + red[1] + red[2] + red[3];
  s2 = red[4] + red[5] + red[6] + red[7];
  const float mu   = s * (1.f / D_MODEL);
  const float var  = s2 * (1.f / D_MODEL) - mu * mu;
  const float rstd = rsqrtf(var + 1e-6f);
  const float4 gv = ((const float4*)g)[t];
  const float4 bv = ((const float4*)b)[t];
  bf16x4 o;
  o[0] = (bf16)((v.x - mu) * rstd * gv.x + bv.x);
  o[1] = (bf16)((v.y - mu) * rstd * gv.y + bv.y);
  o[2] = (bf16)((v.z - mu) * rstd * gv.z + bv.z);
  o[3] = (bf16)((v.w - mu) * rstd * gv.w + bv.w);
  *(bf16x4*)(out + (size_t)row * D_MODEL + t * 4) = o;
}

// ======== pipelined GEMM: BM=256 BN=128 BK=64, 8 waves (4M x 2N) ============
// C = A(MxK) * Bt(NxK)^T + bias. LDS per buf: A[256][64]swz (32KB) + B[128][64]swz (16KB).
// 4 phases/K-tile, counted vmcnt(2) at tile boundary, raw s_barrier (no drain).
// EPI: 1 = fused qkv scatter, 2 = +resid -> fp32, 3 = relu -> bf16
template <int EPI>
__global__ __launch_bounds__(512, 2) void k_gemm(
    const bf16* __restrict__ A, const bf16* __restrict__ Bt,
    const float* __restrict__ bias, const float* __restrict__ biasK,
    const float* __restrict__ biasV, float alpha,
    bf16* __restrict__ obf, float* __restrict__ of32,
    const float* __restrict__ resid,
    int M, int N, int K) {
  __shared__ char lds[2][49152];
  const int t = threadIdx.x, lane = t & 63, w = t >> 6;
  const int wm = w >> 1, wn = w & 1;

  // bijective XCD swizzle (nwg % 8 == 0 for all our grids)
  const int gx = gridDim.x;
  const int nwg = gx * gridDim.y;
  int id = blockIdx.x + blockIdx.y * gx;
  id = (id & 7) * (nwg >> 3) + (id >> 3);
  const int tn = (id % gx) * 128;
  const int tm = (id / gx) * 256;

  // staging source (G4 XOR pre-swizzled): row = w*16 + i*8 + (lane>>3),
  // phys colb = (lane&7)*16, logical col elems = 8*((lane&7)^(lane>>3))
  const int srow = w * 16 + (lane >> 3);
  const int scol = 8 * ((lane & 7) ^ (lane >> 3));
  const bf16* aS = A  + (size_t)(tm + srow) * K + scol;
  const bf16* bS = Bt + (size_t)(tn + srow) * K + scol;
  const int dstOff = w * 2048;  // + i*1024

  // frag read offsets: row*128 + ((s*64 + (lane>>4)*16) ^ ((lane&7)<<4))
  const int rA = (wm * 64 + (lane & 15)) * 128;
  const int rB = 32768 + (wn * 64 + (lane & 15)) * 128;
  const int cS0 = (((lane >> 4) * 16)      ) ^ ((lane & 7) << 4);
  const int cS1 = (64 + ((lane >> 4) * 16) ) ^ ((lane & 7) << 4);

  f32x4 acc[4][4] = {};
  const int KT = K >> 6;

  // prologue: t0 (U0,U1,U2) -> buf0; t1 U0 -> buf1
  gl_lds16(aS,                 lds[0] + dstOff);
  gl_lds16(aS + 8 * K,         lds[0] + dstOff + 1024);
  gl_lds16(aS + 128 * K,       lds[0] + 16384 + dstOff);
  gl_lds16(aS + 136 * K,       lds[0] + 16384 + dstOff + 1024);
  gl_lds16(bS,                 lds[0] + 32768 + dstOff);
  gl_lds16(bS + 8 * K,         lds[0] + 32768 + dstOff + 1024);
  gl_lds16(aS + 64,            lds[1] + dstOff);
  gl_lds16(aS + 8 * K + 64,    lds[1] + dstOff + 1024);
  asm volatile("s_waitcnt vmcnt(2)" ::: "memory");
  __builtin_amdgcn_s_barrier();
  __builtin_amdgcn_sched_barrier(0);

#define RD(buf, off) (*(const bf16x8*)((buf) + (off)))
#define MM(m, n, s) acc[m][n] = __builtin_amdgcn_mfma_f32_16x16x32_bf16(a[m][s], b[n][s], acc[m][n], 0, 0, 0)

  for (int tt = 0; tt < KT; ++tt) {
    char* bufc = lds[tt & 1];
    char* bufn = lds[(tt & 1) ^ 1];
    const int k1 = (tt + 1 < KT ? tt + 1 : KT - 1) * 64;
    const int k2 = (tt + 2 < KT ? tt + 2 : KT - 1) * 64;
    bf16x8 a[4][2], b[4][2];
    // ---- P1: read A m0-1, B s0; stage U1(t+1); MFMA m0-1 x s0
    a[0][0] = RD(bufc, rA + cS0);          a[0][1] = RD(bufc, rA + cS1);
    a[1][0] = RD(bufc, rA + 2048 + cS0);   a[1][1] = RD(bufc, rA + 2048 + cS1);
    b[0][0] = RD(bufc, rB + cS0);
    b[1][0] = RD(bufc, rB + 2048 + cS0);
    b[2][0] = RD(bufc, rB + 4096 + cS0);
    b[3][0] = RD(bufc, rB + 6144 + cS0);
    gl_lds16(aS + 128 * K + k1, bufn + 16384 + dstOff);
    gl_lds16(aS + 136 * K + k1, bufn + 16384 + dstOff + 1024);
    __builtin_amdgcn_s_setprio(1);
    MM(0,0,0); MM(0,1,0); MM(0,2,0); MM(0,3,0);
    MM(1,0,0); MM(1,1,0); MM(1,2,0); MM(1,3,0);
    __builtin_amdgcn_s_setprio(0);
    // ---- P2: read A m2-3, B s1; stage U2(t+1); MFMA m2-3 x s0
    a[2][0] = RD(bufc, rA + 4096 + cS0);   a[2][1] = RD(bufc, rA + 4096 + cS1);
    a[3][0] = RD(bufc, rA + 6144 + cS0);   a[3][1] = RD(bufc, rA + 6144 + cS1);
    b[0][1] = RD(bufc, rB + cS1);
    b[1][1] = RD(bufc, rB + 2048 + cS1);
    b[2][1] = RD(bufc, rB + 4096 + cS1);
    b[3][1] = RD(bufc, rB + 6144 + cS1);
    gl_lds16(bS + k1,         bufn + 32768 + dstOff);
    gl_lds16(bS + 8 * K + k1, bufn + 32768 + dstOff + 1024);
    __builtin_amdgcn_s_setprio(1);
    MM(2,0,0); MM(2,1,0); MM(2,2,0); MM(2,3,0);
    MM(3,0,0); MM(3,1,0); MM(3,2,0); MM(3,3,0);
    __builtin_amdgcn_s_setprio(0);
    // all reads of bufc done -> fence, then stage into bufc
    asm volatile("s_waitcnt lgkmcnt(0)" ::: "memory");
    __builtin_amdgcn_s_barrier();
    __builtin_amdgcn_sched_barrier(0);
    // ---- P3: stage U0(t+2) -> bufc; MFMA m0-1 x s1
    gl_lds16(aS + k2,         bufc + dstOff);
    gl_lds16(aS + 8 * K + k2, bufc + dstOff + 1024);
    __builtin_amdgcn_s_setprio(1);
    MM(0,0,1); MM(0,1,1); MM(0,2,1); MM(0,3,1);
    MM(1,0,1); MM(1,1,1); MM(1,2,1); MM(1,3,1);
    __builtin_amdgcn_s_setprio(0);
    // ---- P4: MFMA m2-3 x s1; boundary wait (counted, never 0)
    __builtin_amdgcn_s_setprio(1);
    MM(2,0,1); MM(2,1,1); MM(2,2,1); MM(2,3,1);
    MM(3,0,1); MM(3,1,1); MM(3,2,1); MM(3,3,1);
    __builtin_amdgcn_s_setprio(0);
    asm volatile("s_waitcnt vmcnt(2)" ::: "memory");
    __builtin_amdgcn_s_barrier();
    __builtin_amdgcn_sched_barrier(0);
  }
#undef RD
#undef MM
  // drain stray clamped staging loads before LDS is released
  asm volatile("s_waitcnt vmcnt(0)" ::: "memory");

  const int row0 = tm + wm * 64 + (lane >> 4) * 4;
  const int col0 = tn + wn * 64 + (lane & 15);
  const int which = tn >> 10;
  const float* bp = (EPI == 1) ? (which == 0 ? bias : (which == 1 ? biasK : biasV)) : bias;
  const float af_ = (EPI == 1) ? (which == 0 ? alpha : 1.f) : alpha;
  bf16* qkvB = (EPI == 1) ? obf + (size_t)which * MTOT * D_MODEL : obf;
#pragma unroll
  for (int n = 0; n < 4; ++n) {
    const int col = col0 + n * 16;
    const float bv = (EPI == 1) ? bp[col & 1023] : bp[col];
#pragma unroll
    for (int m = 0; m < 4; ++m) {
#pragma unroll
      for (int r = 0; r < 4; ++r) {
        const int row = row0 + m * 16 + r;
        float val = acc[m][n][r] + bv;
        if constexpr (EPI == 1) {
          const int bb = row >> 11, ss = row & 2047, hh = (col >> 6) & 15, dd = col & 63;
          qkvB[(((size_t)bb * NH + hh) * SEQ + ss) * DKH + dd] = (bf16)(val * af_);
        } else if constexpr (EPI == 2) {
          const size_t idx = (size_t)row * N + col;
          of32[idx] = resid[idx] + val;
        } else {
          obf[(size_t)row * N + col] = (bf16)fmaxf(val, 0.f);
        }
      }
    }
  }
}

// ---------------- flash attention: swapped-operand 32x32 MFMA ---------------
// q,k,v: (B,H,S,64) bf16 (q pre-scaled by 0.125*log2e). ctx: (B*S,1024) bf16.
__global__ __launch_bounds__(512, 4) void k_attn(
    const bf16* __restrict__ q, const bf16* __restrict__ k, const bf16* __restrict__ v,
    const int* __restrict__ emask, bf16* __restrict__ ctx) {
  __shared__ bf16 Kl[64 * 64];   // swizzled [key][dk]
  __shared__ bf16 Vt[64 * 64];   // swizzled [dk][key]
  __shared__ float Msk[64];
  __shared__ int MskFlag;
  const int t = threadIdx.x, lane = t & 63, w = t >> 6;
  const int hi = lane >> 5;
  const int l31 = lane & 31;
  const unsigned swz = (lane & 7) << 4;
  const int bh = blockIdx.x, b = bh >> 4, h = bh & 15;
  const int q0 = blockIdx.y * 256;
  const bf16* qp = q + (size_t)bh * SEQ * DKH;
  const bf16* kp = k + (size_t)bh * SEQ * DKH;
  const bf16* vp = v + (size_t)bh * SEQ * DKH;
  const int* mp = emask + b * SEQ;

  const int qrow = q0 + w * 32 + l31;
  const bf16* qpr = qp + (size_t)qrow * DKH + hi * 8;
  bf16x8 qf[4];
#pragma unroll
  for (int ks = 0; ks < 4; ++ks) qf[ks] = *(const bf16x8*)(qpr + ks * 16);

  // K stage: linear LDS dest, pre-swizzled global source
  const int krow = w * 8 + (lane >> 3);
  const int kcolE = (((lane & 7) * 16) ^ ((lane >> 3) << 4)) >> 1;
  const bf16* kSrc = kp + (size_t)krow * DKH + kcolE;
  char* kDst = (char*)Kl + w * 1024;

  // V stage: thread -> (d = lane, key-slice w*8..w*8+7); one swizzled b128 write
  const ushort* vU = (const ushort*)vp;
  bf16* vDst = (bf16*)((char*)Vt + (lane << 7) + ((w * 16) ^ ((lane & 7) << 4)));

  f32x16 O0 = {}, O1 = {};
  float mrun = -3e38f, lrun = 0.f;

  for (int kt = 0; kt < SEQ; kt += 64) {
    __syncthreads();
    gl_lds16(kSrc + (size_t)kt * DKH, kDst);
    union { ushort u[8]; bf16x8 v8; } vb;
#pragma unroll
    for (int j = 0; j < 8; ++j)
      vb.u[j] = vU[(size_t)(kt + w * 8 + j) * 64 + lane];
    *(bf16x8*)vDst = vb.v8;
    if (t < 64) {
      const float mv = (mp[kt + t] == 0) ? -1e9f : 0.f;
      Msk[t] = mv;
      const unsigned long long bal = __ballot(mv != 0.f);
      if (t == 0) MskFlag = (bal != 0ull);
    }
    __syncthreads();

    // QK^T (swapped): S^T[key][q], col=lane&31=q
    f32x16 s0 = {}, s1 = {};
#pragma unroll
    for (int ks = 0; ks < 4; ++ks) {
      const bf16x8 kf = *(const bf16x8*)((const char*)Kl + (l31 << 7) + ((ks * 32 + hi * 16) ^ swz));
      s0 = __builtin_amdgcn_mfma_f32_32x32x16_bf16(kf, qf[ks], s0, 0, 0, 0);
    }
#pragma unroll
    for (int ks = 0; ks < 4; ++ks) {
      const bf16x8 kf = *(const bf16x8*)((const char*)Kl + ((32 + l31) << 7) + ((ks * 32 + hi * 16) ^ swz));
      s1 = __builtin_amdgcn_mfma_f32_32x32x16_bf16(kf, qf[ks], s1, 0, 0, 0);
    }
    if (MskFlag) {
#pragma unroll
      for (int g = 0; g < 4; ++g)
#pragma unroll
        for (int j = 0; j < 4; ++j) {
          s0[g * 4 + j] += Msk[g * 8 + hi * 4 + j];
          s1[g * 4 + j] += Msk[32 + g * 8 + hi * 4 + j];
        }
    }

    // online softmax (base-2), T13 defer-max
    float mx = s0[0];
#pragma unroll
    for (int r = 1; r < 16; ++r) mx = fmaxf(mx, s0[r]);
#pragma unroll
    for (int r = 0; r < 16; ++r) mx = fmaxf(mx, s1[r]);
    mx = fmaxf(mx, __shfl_xor(mx, 32));
    if (!__all((int)(mx - mrun <= 8.f))) {
      const float mnew = fmaxf(mrun, mx);
      const float scal = exp2f(mrun - mnew);
      mrun = mnew;
      lrun *= scal;
#pragma unroll
      for (int r = 0; r < 16; ++r) { O0[r] *= scal; O1[r] *= scal; }
    }
    float ts = 0.f;
#pragma unroll
    for (int r = 0; r < 16; ++r) { const float p = exp2f(s0[r] - mrun); s0[r] = p; ts += p; }
#pragma unroll
    for (int r = 0; r < 16; ++r) { const float p = exp2f(s1[r] - mrun); s1[r] = p; ts += p; }
    ts += __shfl_xor(ts, 32);
    lrun += ts;

#define PVSTEP(S, bsel, ks)                                                          \
    {                                                                                \
      unsigned c0 = cvtpk(S[8 * bsel + 0], S[8 * bsel + 1]);                         \
      unsigned c1 = cvtpk(S[8 * bsel + 2], S[8 * bsel + 3]);                         \
      unsigned c2 = cvtpk(S[8 * bsel + 4], S[8 * bsel + 5]);                         \
      unsigned c3 = cvtpk(S[8 * bsel + 6], S[8 * bsel + 7]);                         \
      pl32swap(c0, c2);                                                              \
      pl32swap(c1, c3);                                                              \
      union { unsigned u[4]; bf16x8 vv_; } pu = {{c0, c1, c2, c3}};                  \
      const bf16x8 vf0 = *(const bf16x8*)((const char*)Vt + (l31 << 7) + (((ks) * 32 + hi * 16) ^ swz)); \
      O0 = __builtin_amdgcn_mfma_f32_32x32x16_bf16(vf0, pu.vv_, O0, 0, 0, 0);        \
      const bf16x8 vf1 = *(const bf16x8*)((const char*)Vt + ((32 + l31) << 7) + (((ks) * 32 + hi * 16) ^ swz)); \
      O1 = __builtin_amdgcn_mfma_f32_32x32x16_bf16(vf1, pu.vv_, O1, 0, 0, 0);        \
    }
    PVSTEP(s0, 0, 0)
    PVSTEP(s0, 1, 1)
    PVSTEP(s1, 0, 2)
    PVSTEP(s1, 1, 3)
#undef PVSTEP
  }

  const float rl = 1.f / lrun;
  bf16* cp = ctx + ((size_t)b * SEQ + qrow) * D_MODEL + h * 64;
#pragma unroll
  for (int r = 0; r < 16; ++r) {
    const int d0 = (r & 3) + 8 * (r >> 2) + hi * 4;
    cp[d0]      = (bf16)(O0[r] * rl);
    cp[32 + d0] = (bf16)(O1[r] * rl);
  }
}

// ---------------------------------------------------------------------------
extern "C" void kernel_launch(void* const* d_in, const int* in_sizes, int n_in,
                              void* d_out, int out_size, void* d_ws, size_t ws_size,
                              hipStream_t stream) {
  (void)in_sizes; (void)n_in; (void)out_size; (void)ws_size;
  const float* x    = (const float*)d_in[0];
  const int*   em   = (const int*)d_in[1];
  const float* ln1g = (const float*)d_in[2];
  const float* ln1b = (const float*)d_in[3];
  const float* wq   = (const float*)d_in[4];
  const float* bq   = (const float*)d_in[5];
  const float* wk   = (const float*)d_in[6];
  const float* bk   = (const float*)d_in[7];
  const float* wv   = (const float*)d_in[8];
  const float* bv   = (const float*)d_in[9];
  const float* w0   = (const float*)d_in[10];
  const float* b0   = (const float*)d_in[11];
  const float* ln2g = (const float*)d_in[12];
  const float* ln2b = (const float*)d_in[13];
  const float* w1   = (const float*)d_in[14];
  const float* b1   = (const float*)d_in[15];
  const float* w2   = (const float*)d_in[16];
  const float* b2   = (const float*)d_in[17];
  float* out = (float*)d_out;

  char* ws = (char*)d_ws;
  const size_t MB = 1u << 20;
  bf16* wqT = (bf16*)(ws + 0 * MB);    // [3072][1024] contiguous q,k,v
  bf16* w0T = (bf16*)(ws + 6 * MB);
  bf16* w1T = (bf16*)(ws + 8 * MB);    // [4096][1024]
  bf16* w2T = (bf16*)(ws + 16 * MB);   // [1024][4096]
  bf16* x1  = (bf16*)(ws + 24 * MB);   // LN out (reused for LN2 out)
  bf16* qB  = (bf16*)(ws + 40 * MB);   // (B,H,S,64) x3 contiguous
  bf16* kB  = (bf16*)(ws + 56 * MB);
  bf16* vB  = (bf16*)(ws + 72 * MB);
  bf16* cB  = (bf16*)(ws + 88 * MB);   // ctx (M,1024)
  bf16* hB  = (bf16*)(ws + 40 * MB);   // FFN hidden overlays dead q/k/v/ctx

  k_transp<<<dim3(32, 32),  256, 0, stream>>>(wq, wqT,                   1024, 1024);
  k_transp<<<dim3(32, 32),  256, 0, stream>>>(wk, wqT + 1024 * 1024,     1024, 1024);
  k_transp<<<dim3(32, 32),  256, 0, stream>>>(wv, wqT + 2 * 1024 * 1024, 1024, 1024);
  k_transp<<<dim3(32, 32),  256, 0, stream>>>(w0, w0T, 1024, 1024);
  k_transp<<<dim3(128, 32), 256, 0, stream>>>(w1, w1T, 1024, 4096);
  k_transp<<<dim3(32, 128), 256, 0, stream>>>(w2, w2T, 4096, 1024);

  k_ln<<<MTOT, 256, 0, stream>>>(x, ln1g, ln1b, x1);

  // fused QKV: N=3072; q scaled by 0.125*log2(e) for base-2 softmax
  k_gemm<1><<<dim3(24, MTOT / 256), 512, 0, stream>>>(
      x1, wqT, bq, bk, bv, 0.125f * 1.44269504f, qB, nullptr, nullptr, MTOT, 3072, 1024);

  k_attn<<<dim3(64, 8), 512, 0, stream>>>(qB, kB, vB, em, cB);

  const dim3 g1024(8, MTOT / 256);
  k_gemm<2><<<g1024, 512, 0, stream>>>(cB, w0T, b0, nullptr, nullptr, 1.0f, nullptr, out, x, MTOT, 1024, 1024);

  k_ln<<<MTOT, 256, 0, stream>>>(out, ln2g, ln2b, x1);

  k_gemm<3><<<dim3(32, MTOT / 256), 512, 0, stream>>>(x1, w1T, b1, nullptr, nullptr, 1.0f, hB, nullptr, nullptr, MTOT, 4096, 1024);

  k_gemm<2><<<g1024, 512, 0, stream>>>(hB, w2T, b2, nullptr, nullptr, 1.0f, nullptr, out, out, MTOT, 1024, 4096);
}